// Round 1
// baseline (371.354 us; speedup 1.0000x reference)
//
#include <hip/hip_runtime.h>
#include <hip/hip_bf16.h>

using short8  = __attribute__((ext_vector_type(8))) short;
using floatx4 = __attribute__((ext_vector_type(4))) float;

#define KDIM 768
#define LOG2E 1.4426950408889634f
#define ATT_SCALE 0.125f

__device__ __forceinline__ short f2bf(float f) {
    union { float f; unsigned u; } v; v.f = f;
    unsigned r = v.u + 0x7fffu + ((v.u >> 16) & 1u);
    return (short)(r >> 16);
}

__device__ __forceinline__ void async16(const void* g, void* l) {
    __builtin_amdgcn_global_load_lds((const __attribute__((address_space(1))) void*)g,
                                     (__attribute__((address_space(3))) void*)l, 16, 0, 0);
}

// ---------------- fp32 -> bf16 convert ----------------
__global__ void cvt_f32_bf16(const float* __restrict__ in, short* __restrict__ out, int n) {
    int i = (blockIdx.x * blockDim.x + threadIdx.x) * 4;
    if (i >= n) return;
    float4 v = *(const float4*)(in + i);
    short4 o;
    o.x = f2bf(v.x); o.y = f2bf(v.y); o.z = f2bf(v.z); o.w = f2bf(v.w);
    *(short4*)(out + i) = o;
}

// ---------------- QKV GEMM: C[8192,2304] = X[8192,768] @ W^T, scatter to Q/K/V [bh][s][64] ----------------
__global__ __launch_bounds__(256) void gemm_qkv(
    const short* __restrict__ X, const short* __restrict__ W,
    const float* __restrict__ bias,
    short* __restrict__ Qb, short* __restrict__ Kb, short* __restrict__ Vb)
{
    __shared__ short As[128 * 32];
    __shared__ short Bs[128 * 32];
    int tid = threadIdx.x;
    int w = tid >> 6, l = tid & 63;
    int lane16 = l & 15, quad = l >> 4;
    int wm = w & 1, wn = w >> 1;
    int m0 = blockIdx.y * 128, n0 = blockIdx.x * 128;

    floatx4 acc[4][4] = {};

    int srow = w * 32 + (l >> 2);
    int scol = (l & 3) * 8;
    const short* Xg = X + (size_t)(m0 + srow) * KDIM + scol;
    const short* Wg = W + (size_t)(n0 + srow) * KDIM + scol;
    short* AsW = As + (w * 32) * 32;
    short* BsW = Bs + (w * 32) * 32;

    for (int kb = 0; kb < KDIM; kb += 32) {
        __syncthreads();
        async16(Xg + kb,              AsW);
        async16(Xg + kb + 16 * KDIM,  AsW + 16 * 32);
        async16(Wg + kb,              BsW);
        async16(Wg + kb + 16 * KDIM,  BsW + 16 * 32);
        __syncthreads();
        short8 a[4], b[4];
#pragma unroll
        for (int mt = 0; mt < 4; mt++) a[mt] = *(const short8*)(As + (wm * 64 + mt * 16 + lane16) * 32 + quad * 8);
#pragma unroll
        for (int nt = 0; nt < 4; nt++) b[nt] = *(const short8*)(Bs + (wn * 64 + nt * 16 + lane16) * 32 + quad * 8);
#pragma unroll
        for (int mt = 0; mt < 4; mt++)
#pragma unroll
            for (int nt = 0; nt < 4; nt++)
                acc[mt][nt] = __builtin_amdgcn_mfma_f32_16x16x32_bf16(a[mt], b[nt], acc[mt][nt], 0, 0, 0);
    }

#pragma unroll
    for (int mt = 0; mt < 4; mt++) {
        int row = m0 + wm * 64 + mt * 16 + quad * 4;
#pragma unroll
        for (int nt = 0; nt < 4; nt++) {
            int col = n0 + wn * 64 + nt * 16 + lane16;
            int qkv = (col >= 1536) ? 2 : ((col >= 768) ? 1 : 0);
            int rem = col - qkv * 768;
            int h = rem >> 6, e = rem & 63;
            short* dst = (qkv == 0) ? Qb : ((qkv == 1) ? Kb : Vb);
            float bv = bias[col];
#pragma unroll
            for (int r = 0; r < 4; r++) {
                int i  = row + r;
                int b_ = i >> 11, s_ = i & 2047;
                dst[(((size_t)(b_ * 12 + h)) * 2048 + s_) * 64 + e] = f2bf(acc[mt][nt][r] + bv);
            }
        }
    }
}

// ---------------- flash attention: grid (32 qtiles, 48 bh), 4 waves, Q-tile 64 ----------------
__global__ __launch_bounds__(256) void attn(
    const short* __restrict__ Qb, const short* __restrict__ Kb,
    const short* __restrict__ Vb, short* __restrict__ Ctx)
{
    __shared__ short Ks[64 * 72];     // [key][e], stride 72
    __shared__ short Vt[64 * 72];     // [e][key], stride 72
    __shared__ short Ps[4][16 * 72];  // per-wave P, [qrow][key], stride 72
    int tid = threadIdx.x, w = tid >> 6, l = tid & 63;
    int lane16 = l & 15, quad = l >> 4;
    int qt = blockIdx.x, bh = blockIdx.y;
    const short* Qh = Qb + (size_t)bh * 2048 * 64;
    const short* Kh = Kb + (size_t)bh * 2048 * 64;
    const short* Vh = Vb + (size_t)bh * 2048 * 64;
    int qbase = qt * 64 + w * 16;

    short8 qf[2];
#pragma unroll
    for (int kc = 0; kc < 2; kc++)
        qf[kc] = *(const short8*)(Qh + (size_t)(qbase + lane16) * 64 + kc * 32 + quad * 8);

    float m_r[4], lsum[4];
    floatx4 acc[4] = {};
#pragma unroll
    for (int r = 0; r < 4; r++) { m_r[r] = -1e30f; lsum[r] = 0.f; }

    for (int kt = 0; kt < 32; kt++) {
        __syncthreads();
#pragma unroll
        for (int i = 0; i < 2; i++) {
            int u = tid + i * 256;
            int key = u >> 3, e = (u & 7) * 8;
            short8 kv = *(const short8*)(Kh + (size_t)(kt * 64 + key) * 64 + e);
            *(short8*)(Ks + key * 72 + e) = kv;
            short8 vv = *(const short8*)(Vh + (size_t)(kt * 64 + key) * 64 + e);
#pragma unroll
            for (int j = 0; j < 8; j++) Vt[(e + j) * 72 + key] = vv[j];
        }
        __syncthreads();

        floatx4 s[4];
#pragma unroll
        for (int nt = 0; nt < 4; nt++) {
            floatx4 c = {};
#pragma unroll
            for (int kc = 0; kc < 2; kc++) {
                short8 bfr = *(const short8*)(Ks + (nt * 16 + lane16) * 72 + kc * 32 + quad * 8);
                c = __builtin_amdgcn_mfma_f32_16x16x32_bf16(qf[kc], bfr, c, 0, 0, 0);
            }
            s[nt] = c * (ATT_SCALE * LOG2E);
        }

        float mx[4];
#pragma unroll
        for (int r = 0; r < 4; r++) {
            float m0 = fmaxf(fmaxf(s[0][r], s[1][r]), fmaxf(s[2][r], s[3][r]));
            m0 = fmaxf(m0, __shfl_xor(m0, 1));
            m0 = fmaxf(m0, __shfl_xor(m0, 2));
            m0 = fmaxf(m0, __shfl_xor(m0, 4));
            m0 = fmaxf(m0, __shfl_xor(m0, 8));
            mx[r] = m0;
        }
        float al[4];
#pragma unroll
        for (int r = 0; r < 4; r++) {
            float mn = fmaxf(m_r[r], mx[r]);
            al[r] = exp2f(m_r[r] - mn);
            m_r[r] = mn;
        }
#pragma unroll
        for (int nt = 0; nt < 4; nt++)
#pragma unroll
            for (int r = 0; r < 4; r++)
                s[nt][r] = exp2f(s[nt][r] - m_r[r]);
#pragma unroll
        for (int r = 0; r < 4; r++)
            lsum[r] = lsum[r] * al[r] + s[0][r] + s[1][r] + s[2][r] + s[3][r];
#pragma unroll
        for (int nt = 0; nt < 4; nt++)
#pragma unroll
            for (int r = 0; r < 4; r++)
                acc[nt][r] *= al[r];

#pragma unroll
        for (int nt = 0; nt < 4; nt++)
#pragma unroll
            for (int r = 0; r < 4; r++)
                Ps[w][(quad * 4 + r) * 72 + nt * 16 + lane16] = f2bf(s[nt][r]);

        short8 pa[2];
#pragma unroll
        for (int kc = 0; kc < 2; kc++)
            pa[kc] = *(const short8*)(&Ps[w][lane16 * 72 + kc * 32 + quad * 8]);
#pragma unroll
        for (int nt = 0; nt < 4; nt++)
#pragma unroll
            for (int kc = 0; kc < 2; kc++) {
                short8 vb = *(const short8*)(Vt + (nt * 16 + lane16) * 72 + kc * 32 + quad * 8);
                acc[nt] = __builtin_amdgcn_mfma_f32_16x16x32_bf16(pa[kc], vb, acc[nt], 0, 0, 0);
            }
    }

    float inv[4];
#pragma unroll
    for (int r = 0; r < 4; r++) {
        float t = lsum[r];
        t += __shfl_xor(t, 1);
        t += __shfl_xor(t, 2);
        t += __shfl_xor(t, 4);
        t += __shfl_xor(t, 8);
        inv[r] = 1.0f / t;
    }
    int b_ = bh / 12, h = bh % 12;
#pragma unroll
    for (int nt = 0; nt < 4; nt++)
#pragma unroll
        for (int r = 0; r < 4; r++) {
            int q = qbase + quad * 4 + r;
            int e = nt * 16 + lane16;
            Ctx[((size_t)(b_ * 2048 + q)) * 768 + h * 64 + e] = f2bf(acc[nt][r] * inv[r]);
        }
}

// ---------------- proj GEMM: out[8192,768] = Ctx @ W2^T + b, fp32 out ----------------
__global__ __launch_bounds__(256) void gemm_out(
    const short* __restrict__ Ctx, const short* __restrict__ W,
    const float* __restrict__ bias, float* __restrict__ out)
{
    __shared__ short As[128 * 32];
    __shared__ short Bs[128 * 32];
    int tid = threadIdx.x;
    int w = tid >> 6, l = tid & 63;
    int lane16 = l & 15, quad = l >> 4;
    int wm = w & 1, wn = w >> 1;
    int m0 = blockIdx.y * 128, n0 = blockIdx.x * 128;

    floatx4 acc[4][4] = {};

    int srow = w * 32 + (l >> 2);
    int scol = (l & 3) * 8;
    const short* Xg = Ctx + (size_t)(m0 + srow) * KDIM + scol;
    const short* Wg = W + (size_t)(n0 + srow) * KDIM + scol;
    short* AsW = As + (w * 32) * 32;
    short* BsW = Bs + (w * 32) * 32;

    for (int kb = 0; kb < KDIM; kb += 32) {
        __syncthreads();
        async16(Xg + kb,             AsW);
        async16(Xg + kb + 16 * KDIM, AsW + 16 * 32);
        async16(Wg + kb,             BsW);
        async16(Wg + kb + 16 * KDIM, BsW + 16 * 32);
        __syncthreads();
        short8 a[4], b[4];
#pragma unroll
        for (int mt = 0; mt < 4; mt++) a[mt] = *(const short8*)(As + (wm * 64 + mt * 16 + lane16) * 32 + quad * 8);
#pragma unroll
        for (int nt = 0; nt < 4; nt++) b[nt] = *(const short8*)(Bs + (wn * 64 + nt * 16 + lane16) * 32 + quad * 8);
#pragma unroll
        for (int mt = 0; mt < 4; mt++)
#pragma unroll
            for (int nt = 0; nt < 4; nt++)
                acc[mt][nt] = __builtin_amdgcn_mfma_f32_16x16x32_bf16(a[mt], b[nt], acc[mt][nt], 0, 0, 0);
    }

#pragma unroll
    for (int mt = 0; mt < 4; mt++) {
        int row = m0 + wm * 64 + mt * 16 + quad * 4;
#pragma unroll
        for (int nt = 0; nt < 4; nt++) {
            int col = n0 + wn * 64 + nt * 16 + lane16;
            float bv = bias[col];
#pragma unroll
            for (int r = 0; r < 4; r++)
                out[(size_t)(row + r) * 768 + col] = acc[mt][nt][r] + bv;
        }
    }
}

extern "C" void kernel_launch(void* const* d_in, const int* in_sizes, int n_in,
                              void* d_out, int out_size, void* d_ws, size_t ws_size,
                              hipStream_t stream) {
    const float* hs     = (const float*)d_in[0];
    const float* qkv_w  = (const float*)d_in[1];
    const float* qkv_b  = (const float*)d_in[2];
    const float* proj_w = (const float*)d_in[3];
    const float* proj_b = (const float*)d_in[4];
    float* out = (float*)d_out;

    short* Xb  = (short*)d_ws;                     // 8192*768
    short* W1b = Xb  + (size_t)8192 * 768;         // 2304*768
    short* W2b = W1b + (size_t)2304 * 768;         // 768*768
    short* Qb  = W2b + (size_t)768 * 768;          // 48*2048*64
    short* Kb  = Qb  + (size_t)8192 * 768;
    short* Vb  = Kb  + (size_t)8192 * 768;
    short* Ctx = Vb  + (size_t)8192 * 768;         // 8192*768

    int n1 = 8192 * 768;
    cvt_f32_bf16<<<n1 / 4 / 256, 256, 0, stream>>>(hs, Xb, n1);
    int n2 = 2304 * 768;
    cvt_f32_bf16<<<n2 / 4 / 256, 256, 0, stream>>>(qkv_w, W1b, n2);
    int n3 = 768 * 768;
    cvt_f32_bf16<<<n3 / 4 / 256, 256, 0, stream>>>(proj_w, W2b, n3);

    gemm_qkv<<<dim3(18, 64), 256, 0, stream>>>(Xb, W1b, qkv_b, Qb, Kb, Vb);
    attn<<<dim3(32, 48), 256, 0, stream>>>(Qb, Kb, Vb, Ctx);
    gemm_out<<<dim3(6, 64), 256, 0, stream>>>(Ctx, W2b, proj_b, out);
}

// Round 2
// 257.339 us; speedup vs baseline: 1.4431x; 1.4431x over previous
//
#include <hip/hip_runtime.h>
#include <hip/hip_bf16.h>

using short8  = __attribute__((ext_vector_type(8))) short;
using floatx4 = __attribute__((ext_vector_type(4))) float;

#define KDIM 768
#define QSCALE 0.18033688011112042f   // 0.125 * log2(e)

__device__ __forceinline__ short f2bf(float f) {
    union { float f; unsigned u; } v; v.f = f;
    unsigned r = v.u + 0x7fffu + ((v.u >> 16) & 1u);
    return (short)(r >> 16);
}

__device__ __forceinline__ float fast_exp2(float x) {
#if __has_builtin(__builtin_amdgcn_exp2f)
    return __builtin_amdgcn_exp2f(x);
#else
    return exp2f(x);
#endif
}

__device__ __forceinline__ void async16(const void* g, void* l) {
    __builtin_amdgcn_global_load_lds((const __attribute__((address_space(1))) void*)g,
                                     (__attribute__((address_space(3))) void*)l, 16, 0, 0);
}

// ---------------- fp32 -> bf16 convert ----------------
__global__ void cvt_f32_bf16(const float* __restrict__ in, short* __restrict__ out, int n) {
    int i = (blockIdx.x * blockDim.x + threadIdx.x) * 4;
    if (i >= n) return;
    float4 v = *(const float4*)(in + i);
    short4 o;
    o.x = f2bf(v.x); o.y = f2bf(v.y); o.z = f2bf(v.z); o.w = f2bf(v.w);
    *(short4*)(out + i) = o;
}

// ---------------- QKV GEMM: C[8192,2304] = X @ W^T, scatter to Q/K/V [bh][s][64] ----------------
// Q is pre-scaled by 0.125*log2e so attention scores exit MFMA in exp2 domain.
__global__ __launch_bounds__(256) void gemm_qkv(
    const short* __restrict__ X, const short* __restrict__ W,
    const float* __restrict__ bias,
    short* __restrict__ Qb, short* __restrict__ Kb, short* __restrict__ Vb)
{
    __shared__ short As[128 * 32];
    __shared__ short Bs[128 * 32];
    int tid = threadIdx.x;
    int w = tid >> 6, l = tid & 63;
    int lane16 = l & 15, quad = l >> 4;
    int wm = w & 1, wn = w >> 1;
    int m0 = blockIdx.y * 128, n0 = blockIdx.x * 128;

    floatx4 acc[4][4] = {};

    int srow = w * 32 + (l >> 2);
    int scol = (l & 3) * 8;
    const short* Xg = X + (size_t)(m0 + srow) * KDIM + scol;
    const short* Wg = W + (size_t)(n0 + srow) * KDIM + scol;
    short* AsW = As + (w * 32) * 32;
    short* BsW = Bs + (w * 32) * 32;

    for (int kb = 0; kb < KDIM; kb += 32) {
        __syncthreads();
        async16(Xg + kb,              AsW);
        async16(Xg + kb + 16 * KDIM,  AsW + 16 * 32);
        async16(Wg + kb,              BsW);
        async16(Wg + kb + 16 * KDIM,  BsW + 16 * 32);
        __syncthreads();
        short8 a[4], b[4];
#pragma unroll
        for (int mt = 0; mt < 4; mt++) a[mt] = *(const short8*)(As + (wm * 64 + mt * 16 + lane16) * 32 + quad * 8);
#pragma unroll
        for (int nt = 0; nt < 4; nt++) b[nt] = *(const short8*)(Bs + (wn * 64 + nt * 16 + lane16) * 32 + quad * 8);
#pragma unroll
        for (int mt = 0; mt < 4; mt++)
#pragma unroll
            for (int nt = 0; nt < 4; nt++)
                acc[mt][nt] = __builtin_amdgcn_mfma_f32_16x16x32_bf16(a[mt], b[nt], acc[mt][nt], 0, 0, 0);
    }

#pragma unroll
    for (int mt = 0; mt < 4; mt++) {
        int row = m0 + wm * 64 + mt * 16 + quad * 4;
#pragma unroll
        for (int nt = 0; nt < 4; nt++) {
            int col = n0 + wn * 64 + nt * 16 + lane16;
            int qkv = (col >= 1536) ? 2 : ((col >= 768) ? 1 : 0);
            int rem = col - qkv * 768;
            int h = rem >> 6, e = rem & 63;
            short* dst = (qkv == 0) ? Qb : ((qkv == 1) ? Kb : Vb);
            float sc = (qkv == 0) ? (float)QSCALE : 1.0f;
            float bv = bias[col];
#pragma unroll
            for (int r = 0; r < 4; r++) {
                int i  = row + r;
                int b_ = i >> 11, s_ = i & 2047;
                dst[(((size_t)(b_ * 12 + h)) * 2048 + s_) * 64 + e] = f2bf((acc[mt][nt][r] + bv) * sc);
            }
        }
    }
}

// ---------------- V transpose: Vb [bh][s][64] -> Vt [bh][e=64][s=2048] ----------------
__global__ __launch_bounds__(256) void transpose_v(
    const short* __restrict__ Vb, short* __restrict__ Vt)
{
    __shared__ short T[64 * 66];   // [s_loc][e], stride 66 breaks pow2 banking
    int tid = threadIdx.x;
    int s0 = blockIdx.x * 64, bh = blockIdx.y;
    const short* src = Vb + (size_t)bh * 2048 * 64;
    short* dst = Vt + (size_t)bh * 64 * 2048;

#pragma unroll
    for (int i = 0; i < 2; i++) {
        int slot = i * 256 + tid;
        int s_loc = slot >> 3, ec = slot & 7;
        short8 v = *(const short8*)(src + (size_t)(s0 + s_loc) * 64 + ec * 8);
        *(short8*)(T + s_loc * 66 + ec * 8) = v;
    }
    __syncthreads();
#pragma unroll
    for (int i = 0; i < 2; i++) {
        int slot = i * 256 + tid;
        int e_loc = slot >> 3, sc = slot & 7;
        short8 o;
#pragma unroll
        for (int j = 0; j < 8; j++) o[j] = T[(sc * 8 + j) * 66 + e_loc];
        *(short8*)(dst + (size_t)e_loc * 2048 + s0 + sc * 8) = o;
    }
}

// ---------------- flash attention (no-max softmax, XOR-swizzled LDS tiles) ----------------
// grid (32 qtiles, 48 bh), 4 waves, Q-tile 64 rows (16/wave), K-tile 64.
// LDS tile layout: 512 slots x 16B; slot = row*8 + (chunk ^ (row&7)).
__global__ __launch_bounds__(256) void attn(
    const short* __restrict__ Qb, const short* __restrict__ Kb,
    const short* __restrict__ Vt, short* __restrict__ Ctx)
{
    __shared__ short Ks[512 * 8];      // K tile: row=key, chunk over e
    __shared__ short Vs[512 * 8];      // V tile: row=e,   chunk over key
    __shared__ short Ps[4][128 * 8];   // per-wave P: row=q(16), chunk over key
    int tid = threadIdx.x, w = tid >> 6, l = tid & 63;
    int lane16 = l & 15, quad = l >> 4;
    int qt = blockIdx.x, bh = blockIdx.y;
    const short* Qh  = Qb + (size_t)bh * 2048 * 64;
    const short* Kh  = Kb + (size_t)bh * 2048 * 64;
    const short* Vth = Vt + (size_t)bh * 64 * 2048;
    int qbase = qt * 64 + w * 16;
    short* Psw = &Ps[w][0];

    // staging source addresses (slot fixed per thread; kt advances the offset)
    const short* kSrc[2];
    const short* vSrc[2];
    short* kDst[2];
    short* vDst[2];
#pragma unroll
    for (int i = 0; i < 2; i++) {
        int slot = i * 256 + tid;
        int row = slot >> 3;
        int g = (slot & 7) ^ (row & 7);
        kSrc[i] = Kh + (size_t)row * 64 + g * 8;          // + kt*64*64
        vSrc[i] = Vth + (size_t)row * 2048 + g * 8;       // + kt*64
        kDst[i] = Ks + (size_t)(i * 256 + w * 64) * 8;    // wave-uniform base
        vDst[i] = Vs + (size_t)(i * 256 + w * 64) * 8;
    }

    short8 qf[2];
#pragma unroll
    for (int kc = 0; kc < 2; kc++)
        qf[kc] = *(const short8*)(Qh + (size_t)(qbase + lane16) * 64 + kc * 32 + quad * 8);

    float lsum[4] = {0.f, 0.f, 0.f, 0.f};
    floatx4 acc[4] = {};

    for (int kt = 0; kt < 32; kt++) {
        __syncthreads();
#pragma unroll
        for (int i = 0; i < 2; i++) {
            async16(kSrc[i] + (size_t)kt * 64 * 64, kDst[i]);
            async16(vSrc[i] + (size_t)kt * 64,      vDst[i]);
        }
        __syncthreads();

        // QK^T: scores already in exp2 domain (Q pre-scaled)
        floatx4 s[4];
#pragma unroll
        for (int nt = 0; nt < 4; nt++) {
            floatx4 c = {};
            int row = nt * 16 + lane16;
#pragma unroll
            for (int kc = 0; kc < 2; kc++) {
                int chunk = kc * 4 + quad;
                short8 kf = *(const short8*)(Ks + (size_t)(row * 8 + (chunk ^ (row & 7))) * 8);
                c = __builtin_amdgcn_mfma_f32_16x16x32_bf16(qf[kc], kf, c, 0, 0, 0);
            }
            s[nt] = c;
        }

        // exp2 + row-sum accumulate + P store (swizzled, per-wave region)
#pragma unroll
        for (int nt = 0; nt < 4; nt++) {
            int key = nt * 16 + lane16;
            int chunk = key >> 3, pos = key & 7;
#pragma unroll
            for (int r = 0; r < 4; r++) {
                float p = fast_exp2(s[nt][r]);
                lsum[r] += p;
                int row = quad * 4 + r;
                Psw[(row * 8 + (chunk ^ (row & 7))) * 8 + pos] = f2bf(p);
            }
        }

        short8 pa[2];
#pragma unroll
        for (int kc = 0; kc < 2; kc++) {
            int chunk = kc * 4 + quad;
            int row = lane16;
            pa[kc] = *(const short8*)(Psw + (size_t)(row * 8 + (chunk ^ (row & 7))) * 8);
        }
#pragma unroll
        for (int nt = 0; nt < 4; nt++) {
            int row = nt * 16 + lane16;
#pragma unroll
            for (int kc = 0; kc < 2; kc++) {
                int chunk = kc * 4 + quad;
                short8 vf = *(const short8*)(Vs + (size_t)(row * 8 + (chunk ^ (row & 7))) * 8);
                acc[nt] = __builtin_amdgcn_mfma_f32_16x16x32_bf16(pa[kc], vf, acc[nt], 0, 0, 0);
            }
        }
    }

    float inv[4];
#pragma unroll
    for (int r = 0; r < 4; r++) {
        float t = lsum[r];
        t += __shfl_xor(t, 1);
        t += __shfl_xor(t, 2);
        t += __shfl_xor(t, 4);
        t += __shfl_xor(t, 8);
        inv[r] = 1.0f / t;
    }
    int b_ = bh / 12, h = bh % 12;
#pragma unroll
    for (int nt = 0; nt < 4; nt++)
#pragma unroll
        for (int r = 0; r < 4; r++) {
            int q = qbase + quad * 4 + r;
            int e = nt * 16 + lane16;
            Ctx[((size_t)(b_ * 2048 + q)) * 768 + h * 64 + e] = f2bf(acc[nt][r] * inv[r]);
        }
}

// ---------------- proj GEMM: out[8192,768] = Ctx @ W2^T + b, fp32 out ----------------
__global__ __launch_bounds__(256) void gemm_out(
    const short* __restrict__ Ctx, const short* __restrict__ W,
    const float* __restrict__ bias, float* __restrict__ out)
{
    __shared__ short As[128 * 32];
    __shared__ short Bs[128 * 32];
    int tid = threadIdx.x;
    int w = tid >> 6, l = tid & 63;
    int lane16 = l & 15, quad = l >> 4;
    int wm = w & 1, wn = w >> 1;
    int m0 = blockIdx.y * 128, n0 = blockIdx.x * 128;

    floatx4 acc[4][4] = {};

    int srow = w * 32 + (l >> 2);
    int scol = (l & 3) * 8;
    const short* Xg = Ctx + (size_t)(m0 + srow) * KDIM + scol;
    const short* Wg = W + (size_t)(n0 + srow) * KDIM + scol;
    short* AsW = As + (w * 32) * 32;
    short* BsW = Bs + (w * 32) * 32;

    for (int kb = 0; kb < KDIM; kb += 32) {
        __syncthreads();
        async16(Xg + kb,             AsW);
        async16(Xg + kb + 16 * KDIM, AsW + 16 * 32);
        async16(Wg + kb,             BsW);
        async16(Wg + kb + 16 * KDIM, BsW + 16 * 32);
        __syncthreads();
        short8 a[4], b[4];
#pragma unroll
        for (int mt = 0; mt < 4; mt++) a[mt] = *(const short8*)(As + (wm * 64 + mt * 16 + lane16) * 32 + quad * 8);
#pragma unroll
        for (int nt = 0; nt < 4; nt++) b[nt] = *(const short8*)(Bs + (wn * 64 + nt * 16 + lane16) * 32 + quad * 8);
#pragma unroll
        for (int mt = 0; mt < 4; mt++)
#pragma unroll
            for (int nt = 0; nt < 4; nt++)
                acc[mt][nt] = __builtin_amdgcn_mfma_f32_16x16x32_bf16(a[mt], b[nt], acc[mt][nt], 0, 0, 0);
    }

#pragma unroll
    for (int mt = 0; mt < 4; mt++) {
        int row = m0 + wm * 64 + mt * 16 + quad * 4;
#pragma unroll
        for (int nt = 0; nt < 4; nt++) {
            int col = n0 + wn * 64 + nt * 16 + lane16;
            float bv = bias[col];
#pragma unroll
            for (int r = 0; r < 4; r++)
                out[(size_t)(row + r) * 768 + col] = acc[mt][nt][r] + bv;
        }
    }
}

extern "C" void kernel_launch(void* const* d_in, const int* in_sizes, int n_in,
                              void* d_out, int out_size, void* d_ws, size_t ws_size,
                              hipStream_t stream) {
    const float* hs     = (const float*)d_in[0];
    const float* qkv_w  = (const float*)d_in[1];
    const float* qkv_b  = (const float*)d_in[2];
    const float* proj_w = (const float*)d_in[3];
    const float* proj_b = (const float*)d_in[4];
    float* out = (float*)d_out;

    short* Xb  = (short*)d_ws;                     // 8192*768 (dead after gemm_qkv; reused as Vt)
    short* W1b = Xb  + (size_t)8192 * 768;         // 2304*768
    short* W2b = W1b + (size_t)2304 * 768;         // 768*768
    short* Qb  = W2b + (size_t)768 * 768;          // 48*2048*64
    short* Kb  = Qb  + (size_t)8192 * 768;
    short* Vb  = Kb  + (size_t)8192 * 768;
    short* Ctx = Vb  + (size_t)8192 * 768;         // 8192*768
    short* Vt  = Xb;                               // [bh][64][2048], overlays dead Xb

    int n1 = 8192 * 768;
    cvt_f32_bf16<<<n1 / 4 / 256, 256, 0, stream>>>(hs, Xb, n1);
    int n2 = 2304 * 768;
    cvt_f32_bf16<<<n2 / 4 / 256, 256, 0, stream>>>(qkv_w, W1b, n2);
    int n3 = 768 * 768;
    cvt_f32_bf16<<<n3 / 4 / 256, 256, 0, stream>>>(proj_w, W2b, n3);

    gemm_qkv<<<dim3(18, 64), 256, 0, stream>>>(Xb, W1b, qkv_b, Qb, Kb, Vb);
    transpose_v<<<dim3(32, 48), 256, 0, stream>>>(Vb, Vt);
    attn<<<dim3(32, 48), 256, 0, stream>>>(Qb, Kb, Vt, Ctx);
    gemm_out<<<dim3(6, 64), 256, 0, stream>>>(Ctx, W2b, proj_b, out);
}

// Round 3
// 238.592 us; speedup vs baseline: 1.5564x; 1.0786x over previous
//
#include <hip/hip_runtime.h>
#include <hip/hip_bf16.h>

using short8   = __attribute__((ext_vector_type(8))) short;
using floatx4  = __attribute__((ext_vector_type(4))) float;
using floatx16 = __attribute__((ext_vector_type(16))) float;

#define KDIM 768
#define QSCALE 0.18033688011112042f   // 0.125 * log2(e)

__device__ __forceinline__ short f2bf(float f) {
    union { float f; unsigned u; } v; v.f = f;
    unsigned r = v.u + 0x7fffu + ((v.u >> 16) & 1u);
    return (short)(r >> 16);
}

__device__ __forceinline__ unsigned pack2bf(float a, float b) {
    __hip_bfloat162 h = __float22bfloat162_rn(float2{a, b});
    union { __hip_bfloat162 h; unsigned u; } c; c.h = h;
    return c.u;
}

__device__ __forceinline__ float fast_exp2(float x) {
#if __has_builtin(__builtin_amdgcn_exp2f)
    return __builtin_amdgcn_exp2f(x);
#else
    return exp2f(x);
#endif
}

__device__ __forceinline__ void async16(const void* g, void* l) {
    __builtin_amdgcn_global_load_lds((const __attribute__((address_space(1))) void*)g,
                                     (__attribute__((address_space(3))) void*)l, 16, 0, 0);
}

// ---------------- fp32 -> bf16 convert ----------------
__global__ void cvt_f32_bf16(const float* __restrict__ in, short* __restrict__ out, int n) {
    int i = (blockIdx.x * blockDim.x + threadIdx.x) * 4;
    if (i >= n) return;
    float4 v = *(const float4*)(in + i);
    short4 o;
    o.x = f2bf(v.x); o.y = f2bf(v.y); o.z = f2bf(v.z); o.w = f2bf(v.w);
    *(short4*)(out + i) = o;
}

// ---------------- QKV GEMM: C[8192,2304] = X @ W^T, scatter to Q/K/V [bh][s][64] ----------------
__global__ __launch_bounds__(256) void gemm_qkv(
    const short* __restrict__ X, const short* __restrict__ W,
    const float* __restrict__ bias,
    short* __restrict__ Qb, short* __restrict__ Kb, short* __restrict__ Vb)
{
    __shared__ short As[128 * 32];
    __shared__ short Bs[128 * 32];
    int tid = threadIdx.x;
    int w = tid >> 6, l = tid & 63;
    int lane16 = l & 15, quad = l >> 4;
    int wm = w & 1, wn = w >> 1;
    int m0 = blockIdx.y * 128, n0 = blockIdx.x * 128;

    floatx4 acc[4][4] = {};

    int srow = w * 32 + (l >> 2);
    int scol = (l & 3) * 8;
    const short* Xg = X + (size_t)(m0 + srow) * KDIM + scol;
    const short* Wg = W + (size_t)(n0 + srow) * KDIM + scol;
    short* AsW = As + (w * 32) * 32;
    short* BsW = Bs + (w * 32) * 32;

    for (int kb = 0; kb < KDIM; kb += 32) {
        __syncthreads();
        async16(Xg + kb,              AsW);
        async16(Xg + kb + 16 * KDIM,  AsW + 16 * 32);
        async16(Wg + kb,              BsW);
        async16(Wg + kb + 16 * KDIM,  BsW + 16 * 32);
        __syncthreads();
        short8 a[4], b[4];
#pragma unroll
        for (int mt = 0; mt < 4; mt++) a[mt] = *(const short8*)(As + (wm * 64 + mt * 16 + lane16) * 32 + quad * 8);
#pragma unroll
        for (int nt = 0; nt < 4; nt++) b[nt] = *(const short8*)(Bs + (wn * 64 + nt * 16 + lane16) * 32 + quad * 8);
#pragma unroll
        for (int mt = 0; mt < 4; mt++)
#pragma unroll
            for (int nt = 0; nt < 4; nt++)
                acc[mt][nt] = __builtin_amdgcn_mfma_f32_16x16x32_bf16(a[mt], b[nt], acc[mt][nt], 0, 0, 0);
    }

#pragma unroll
    for (int mt = 0; mt < 4; mt++) {
        int row = m0 + wm * 64 + mt * 16 + quad * 4;
#pragma unroll
        for (int nt = 0; nt < 4; nt++) {
            int col = n0 + wn * 64 + nt * 16 + lane16;
            int qkv = (col >= 1536) ? 2 : ((col >= 768) ? 1 : 0);
            int rem = col - qkv * 768;
            int h = rem >> 6, e = rem & 63;
            short* dst = (qkv == 0) ? Qb : ((qkv == 1) ? Kb : Vb);
            float sc = (qkv == 0) ? (float)QSCALE : 1.0f;
            float bv = bias[col];
#pragma unroll
            for (int r = 0; r < 4; r++) {
                int i  = row + r;
                int b_ = i >> 11, s_ = i & 2047;
                dst[(((size_t)(b_ * 12 + h)) * 2048 + s_) * 64 + e] = f2bf((acc[mt][nt][r] + bv) * sc);
            }
        }
    }
}

// ---------------- V transpose: Vb [bh][s][64] -> Vt [bh][e=64][s=2048] ----------------
__global__ __launch_bounds__(256) void transpose_v(
    const short* __restrict__ Vb, short* __restrict__ Vt)
{
    __shared__ short T[64 * 66];
    int tid = threadIdx.x;
    int s0 = blockIdx.x * 64, bh = blockIdx.y;
    const short* src = Vb + (size_t)bh * 2048 * 64;
    short* dst = Vt + (size_t)bh * 64 * 2048;

#pragma unroll
    for (int i = 0; i < 2; i++) {
        int slot = i * 256 + tid;
        int s_loc = slot >> 3, ec = slot & 7;
        short8 v = *(const short8*)(src + (size_t)(s0 + s_loc) * 64 + ec * 8);
        *(short8*)(T + s_loc * 66 + ec * 8) = v;
    }
    __syncthreads();
#pragma unroll
    for (int i = 0; i < 2; i++) {
        int slot = i * 256 + tid;
        int e_loc = slot >> 3, sc = slot & 7;
        short8 o;
#pragma unroll
        for (int j = 0; j < 8; j++) o[j] = T[(sc * 8 + j) * 66 + e_loc];
        *(short8*)(dst + (size_t)e_loc * 2048 + s0 + sc * 8) = o;
    }
}

// ---------------- flash attention, 32x32x16 MFMA ----------------
// grid (16 qtiles, 48 bh), 4 waves; Q-tile 128 (32 rows/wave), K-tile 64.
// LDS tiles: 16B slots, slot = row*8 + (chunk ^ (row&7)).
// 32x32x16 layouts: A/B [m=lane&31][k=(lane>>5)*8+j]; C/D col=lane&31,
// row=(reg&3)+8*(reg>>2)+4*(lane>>5).
__global__ __launch_bounds__(256, 3) void attn(
    const short* __restrict__ Qb, const short* __restrict__ Kb,
    const short* __restrict__ Vt, short* __restrict__ Ctx)
{
    __shared__ short Ks[512 * 8];      // K tile: [key 64][e 64]
    __shared__ short Vs[512 * 8];      // V^T tile: [e 64][key 64]
    __shared__ short Ps[4][256 * 8];   // per-wave P: [q 32][key 64]
    int tid = threadIdx.x, w = tid >> 6, l = tid & 63;
    int l32 = l & 31, half = l >> 5;
    int qt = blockIdx.x, bh = blockIdx.y;
    const short* Qh  = Qb + (size_t)bh * 2048 * 64;
    const short* Kh  = Kb + (size_t)bh * 2048 * 64;
    const short* Vth = Vt + (size_t)bh * 64 * 2048;
    int qbase = qt * 128 + w * 32;
    short* Psw = &Ps[w][0];

    // staging (global_load_lds): slot fixed per thread, kt advances offset
    const short* kSrc[2];
    const short* vSrc[2];
    short* kDst[2];
    short* vDst[2];
#pragma unroll
    for (int i = 0; i < 2; i++) {
        int slot = i * 256 + tid;
        int row = slot >> 3;
        int g = (slot & 7) ^ (row & 7);
        kSrc[i] = Kh + (size_t)row * 64 + g * 8;
        vSrc[i] = Vth + (size_t)row * 2048 + g * 8;
        kDst[i] = Ks + (size_t)(i * 256 + w * 64) * 8;
        vDst[i] = Vs + (size_t)(i * 256 + w * 64) * 8;
    }

    // Q fragments: 32 q-rows per wave, held in registers
    short8 qf[4];
#pragma unroll
    for (int ks = 0; ks < 4; ks++)
        qf[ks] = *(const short8*)(Qh + (size_t)(qbase + l32) * 64 + ks * 16 + half * 8);

    float lsum[16];
#pragma unroll
    for (int r = 0; r < 16; r++) lsum[r] = 0.f;
    floatx16 acc[2] = {};

    for (int kt = 0; kt < 32; kt++) {
        __syncthreads();
#pragma unroll
        for (int i = 0; i < 2; i++) {
            async16(kSrc[i] + (size_t)kt * 64 * 64, kDst[i]);
            async16(vSrc[i] + (size_t)kt * 64,      vDst[i]);
        }
        __syncthreads();

        // QK^T (scores exit in exp2 domain; Q pre-scaled)
        floatx16 s[2];
#pragma unroll
        for (int nt = 0; nt < 2; nt++) {
            floatx16 c = {};
#pragma unroll
            for (int ks = 0; ks < 4; ks++) {
                int row = nt * 32 + l32;
                int chunk = ks * 2 + half;
                short8 kf = *(const short8*)(Ks + (size_t)(row * 8 + (chunk ^ (row & 7))) * 8);
                c = __builtin_amdgcn_mfma_f32_32x32x16_bf16(qf[ks], kf, c, 0, 0, 0);
            }
            s[nt] = c;
        }

        // exp2 + row-sum + packed P store (per-wave swizzled region)
#pragma unroll
        for (int nt = 0; nt < 2; nt++) {
            int key = nt * 32 + l32;
            int chunk = key >> 3, pos = key & 7;
#pragma unroll
            for (int r = 0; r < 16; r += 2) {
                float p0 = fast_exp2(s[nt][r]);
                float p1 = fast_exp2(s[nt][r + 1]);
                lsum[r]     += p0;
                lsum[r + 1] += p1;
                int row0 = (r & 3) + 8 * (r >> 2) + 4 * half;
                unsigned pk = pack2bf(p0, p1);
                Psw[(size_t)(row0 * 8 + (chunk ^ (row0 & 7))) * 8 + pos]       = (short)(pk & 0xffff);
                Psw[(size_t)((row0 + 1) * 8 + (chunk ^ ((row0 + 1) & 7))) * 8 + pos] = (short)(pk >> 16);
            }
        }

        // PV: A = P[q][key], B = V^T[e][key]
        short8 pa[4];
#pragma unroll
        for (int ks = 0; ks < 4; ks++) {
            int chunk = ks * 2 + half;
            pa[ks] = *(const short8*)(Psw + (size_t)(l32 * 8 + (chunk ^ (l32 & 7))) * 8);
        }
#pragma unroll
        for (int nt = 0; nt < 2; nt++) {
#pragma unroll
            for (int ks = 0; ks < 4; ks++) {
                int row = nt * 32 + l32;
                int chunk = ks * 2 + half;
                short8 vf = *(const short8*)(Vs + (size_t)(row * 8 + (chunk ^ (row & 7))) * 8);
                acc[nt] = __builtin_amdgcn_mfma_f32_32x32x16_bf16(pa[ks], vf, acc[nt], 0, 0, 0);
            }
        }
    }

    float inv[16];
#pragma unroll
    for (int r = 0; r < 16; r++) {
        float t = lsum[r];
        t += __shfl_xor(t, 1);
        t += __shfl_xor(t, 2);
        t += __shfl_xor(t, 4);
        t += __shfl_xor(t, 8);
        t += __shfl_xor(t, 16);
        inv[r] = 1.0f / t;
    }
    int b_ = bh / 12, h = bh % 12;
#pragma unroll
    for (int nt = 0; nt < 2; nt++)
#pragma unroll
        for (int r = 0; r < 16; r++) {
            int q = qbase + (r & 3) + 8 * (r >> 2) + 4 * half;
            int e = nt * 32 + l32;
            Ctx[((size_t)(b_ * 2048 + q)) * 768 + h * 64 + e] = f2bf(acc[nt][r] * inv[r]);
        }
}

// ---------------- proj GEMM: out[8192,768] = Ctx @ W2^T + b, fp32 out ----------------
__global__ __launch_bounds__(256) void gemm_out(
    const short* __restrict__ Ctx, const short* __restrict__ W,
    const float* __restrict__ bias, float* __restrict__ out)
{
    __shared__ short As[128 * 32];
    __shared__ short Bs[128 * 32];
    int tid = threadIdx.x;
    int w = tid >> 6, l = tid & 63;
    int lane16 = l & 15, quad = l >> 4;
    int wm = w & 1, wn = w >> 1;
    int m0 = blockIdx.y * 128, n0 = blockIdx.x * 128;

    floatx4 acc[4][4] = {};

    int srow = w * 32 + (l >> 2);
    int scol = (l & 3) * 8;
    const short* Xg = Ctx + (size_t)(m0 + srow) * KDIM + scol;
    const short* Wg = W + (size_t)(n0 + srow) * KDIM + scol;
    short* AsW = As + (w * 32) * 32;
    short* BsW = Bs + (w * 32) * 32;

    for (int kb = 0; kb < KDIM; kb += 32) {
        __syncthreads();
        async16(Xg + kb,             AsW);
        async16(Xg + kb + 16 * KDIM, AsW + 16 * 32);
        async16(Wg + kb,             BsW);
        async16(Wg + kb + 16 * KDIM, BsW + 16 * 32);
        __syncthreads();
        short8 a[4], b[4];
#pragma unroll
        for (int mt = 0; mt < 4; mt++) a[mt] = *(const short8*)(As + (wm * 64 + mt * 16 + lane16) * 32 + quad * 8);
#pragma unroll
        for (int nt = 0; nt < 4; nt++) b[nt] = *(const short8*)(Bs + (wn * 64 + nt * 16 + lane16) * 32 + quad * 8);
#pragma unroll
        for (int mt = 0; mt < 4; mt++)
#pragma unroll
            for (int nt = 0; nt < 4; nt++)
                acc[mt][nt] = __builtin_amdgcn_mfma_f32_16x16x32_bf16(a[mt], b[nt], acc[mt][nt], 0, 0, 0);
    }

#pragma unroll
    for (int mt = 0; mt < 4; mt++) {
        int row = m0 + wm * 64 + mt * 16 + quad * 4;
#pragma unroll
        for (int nt = 0; nt < 4; nt++) {
            int col = n0 + wn * 64 + nt * 16 + lane16;
            float bv = bias[col];
#pragma unroll
            for (int r = 0; r < 4; r++)
                out[(size_t)(row + r) * 768 + col] = acc[mt][nt][r] + bv;
        }
    }
}

extern "C" void kernel_launch(void* const* d_in, const int* in_sizes, int n_in,
                              void* d_out, int out_size, void* d_ws, size_t ws_size,
                              hipStream_t stream) {
    const float* hs     = (const float*)d_in[0];
    const float* qkv_w  = (const float*)d_in[1];
    const float* qkv_b  = (const float*)d_in[2];
    const float* proj_w = (const float*)d_in[3];
    const float* proj_b = (const float*)d_in[4];
    float* out = (float*)d_out;

    short* Xb  = (short*)d_ws;                     // 8192*768 (dead after gemm_qkv; reused as Vt)
    short* W1b = Xb  + (size_t)8192 * 768;         // 2304*768
    short* W2b = W1b + (size_t)2304 * 768;         // 768*768
    short* Qb  = W2b + (size_t)768 * 768;          // 48*2048*64
    short* Kb  = Qb  + (size_t)8192 * 768;
    short* Vb  = Kb  + (size_t)8192 * 768;
    short* Ctx = Vb  + (size_t)8192 * 768;         // 8192*768
    short* Vt  = Xb;                               // [bh][64][2048], overlays dead Xb

    int n1 = 8192 * 768;
    cvt_f32_bf16<<<n1 / 4 / 256, 256, 0, stream>>>(hs, Xb, n1);
    int n2 = 2304 * 768;
    cvt_f32_bf16<<<n2 / 4 / 256, 256, 0, stream>>>(qkv_w, W1b, n2);
    int n3 = 768 * 768;
    cvt_f32_bf16<<<n3 / 4 / 256, 256, 0, stream>>>(proj_w, W2b, n3);

    gemm_qkv<<<dim3(18, 64), 256, 0, stream>>>(Xb, W1b, qkv_b, Qb, Kb, Vb);
    transpose_v<<<dim3(32, 48), 256, 0, stream>>>(Vb, Vt);
    attn<<<dim3(16, 48), 256, 0, stream>>>(Qb, Kb, Vt, Ctx);
    gemm_out<<<dim3(6, 64), 256, 0, stream>>>(Ctx, W2b, proj_b, out);
}